// Round 8
// baseline (32654.059 us; speedup 1.0000x reference)
//
#include <hip/hip_runtime.h>

typedef float f32x4 __attribute__((ext_vector_type(4)));
typedef short s16x8 __attribute__((ext_vector_type(8)));
typedef _Float16 h2v __attribute__((ext_vector_type(2)));

#define MINI(a,b) ((a)<(b)?(a):(b))
#define MAXI(a,b) ((a)>(b)?(a):(b))

static __device__ __forceinline__ float bf2f(unsigned short u){
  union { unsigned int i; float f; } x; x.i = ((unsigned int)u) << 16; return x.f;
}
static __device__ __forceinline__ unsigned short f2bf(float f){
  union { float f; unsigned int i; } x; x.f = f;
  return (unsigned short)((x.i + 0x7fffu + ((x.i >> 16) & 1u)) >> 16);
}
static __device__ __forceinline__ float asf(unsigned int u){
  union { unsigned int i; float f; } c; c.i = u; return c.f;
}
static __device__ __forceinline__ float sigm(float x){ return 1.f / (1.f + __expf(-x)); }
static __device__ __forceinline__ float tanhf_(float x){ return 1.f - 2.f / (1.f + __expf(2.f * x)); }

// agent-scope (sc1) loads: bypass per-XCD L2, served by LLC. Used for K/V so
// the streaming attention traffic does not evict the weight working set in L2.
static __device__ __forceinline__ unsigned int aldu(const void* p){
  return __hip_atomic_load((const unsigned int*)p, __ATOMIC_RELAXED, __HIP_MEMORY_SCOPE_AGENT);
}

// f16 pack/dot helpers. Weights are stored as packed f16 k-pairs (u32).
static __device__ __forceinline__ unsigned int pkh(float a, float b){
  union { _Float16 h[2]; unsigned int u; } c;
  c.h[0] = (_Float16)a; c.h[1] = (_Float16)b; return c.u;
}
static __device__ __forceinline__ float dot2(unsigned int x, unsigned int w, float acc){
#if __has_builtin(__builtin_amdgcn_fdot2)
  union { unsigned int u; h2v h; } a, b; a.u = x; b.u = w;
  return __builtin_amdgcn_fdot2(a.h, b.h, acc, false);
#else
  union { unsigned int u; _Float16 h[2]; } a, b; a.u = x; b.u = w;
  return acc + (float)a.h[0]*(float)b.h[0] + (float)a.h[1]*(float)b.h[1];
#endif
}

// ---------------------------------------------------------------------------
// K1: fold Wq into key projection (Bmat bf16), biases.
// ---------------------------------------------------------------------------
__global__ void k_prepw(const float* Wk, const float* Wq, const float* Wv,
                        const float* bk, const float* bq, const float* bv,
                        unsigned short* Bm, float* bvec, float* wkb, float* cb0){
  const int k = blockIdx.x;     // 512
  const int t = threadIdx.x;    // 256
  const float scale = 0.0625f;
  float acc = 0.f;
  for (int p = 0; p < 256; p++) acc += Wk[k*256+p] * Wq[t*256+p];
  Bm[(size_t)k*512 + t]       = f2bf(acc * scale);
  Bm[(size_t)k*512 + 256 + t] = f2bf(Wv[k*256+t]);
  __shared__ float red[256];
  red[t] = Wk[k*256+t] * bq[t];
  __syncthreads();
  for (int o = 128; o > 0; o >>= 1){ if (t < o) red[t] += red[t+o]; __syncthreads(); }
  if (t == 0) wkb[k] = red[0] * scale;
  if (k == 0){
    float a2 = 0.f;
    for (int p = 0; p < 256; p++) a2 += bk[p] * Wq[t*256+p];
    bvec[t] = a2 * scale;
    bvec[256+t] = bv[t];
    __syncthreads();
    red[t] = bk[t] * bq[t];
    __syncthreads();
    for (int o = 128; o > 0; o >>= 1){ if (t < o) red[t] += red[t+o]; __syncthreads(); }
    if (t == 0) *cb0 = red[0] * scale;
  }
}

__global__ void k_keybias(const float* enc, const float* wkb, const float* cb0,
                          float* keybias){
  const int m = blockIdx.x*8 + (threadIdx.x >> 6);
  const int lane = threadIdx.x & 63;
  float p = 0.f;
  #pragma unroll
  for (int j = 0; j < 8; j++){ int k = lane + 64*j; p += enc[(size_t)m*512 + k] * wkb[k]; }
  #pragma unroll
  for (int o = 1; o < 64; o <<= 1) p += __shfl_xor(p, o, 64);
  if (lane == 0) keybias[m] = p + *cb0;
}

// ---------------------------------------------------------------------------
// K3: init ctx0[b][d] = (enc[b,0,:] @ Wk + bk)[d]
// ---------------------------------------------------------------------------
__global__ void k_init(const float* enc, const float* Wk, const float* bk, float* ctx0){
  const int b = blockIdx.x, t = threadIdx.x;  // 64 x 256
  float acc = bk[t];
  const float* er = enc + (size_t)b*800*512;
  for (int k = 0; k < 512; k++) acc += er[k] * Wk[(size_t)k*256 + t];
  ctx0[b*256 + t] = acc;
}

// ---------------------------------------------------------------------------
// K4: MFMA bf16 GEMM; epilogue scatters to keyT[b][k][s] and val[b][s][d].
// ---------------------------------------------------------------------------
__global__ __launch_bounds__(256) void k_gemm(const float* enc, const unsigned short* Bm,
                                              const float* bvec,
                                              unsigned short* kT, unsigned short* vl){
  __shared__ unsigned short Al[64][40];
  __shared__ unsigned short Bl[64][40];
  const int tid = threadIdx.x, w = tid >> 6, lane = tid & 63;
  const int M0 = (blockIdx.x >> 3) * 64;
  const int N0 = (blockIdx.x & 7) * 64;
  f32x4 acc[4] = {};
  const int mrow = w*16 + (lane & 15);
  const int koff = (lane >> 4) * 8;
  for (int k0 = 0; k0 < 512; k0 += 32){
    #pragma unroll
    for (int it = 0; it < 2; it++){
      int row = (tid >> 3) + it*32, kq = (tid & 7) * 4;
      float4 v = *(const float4*)(enc + (size_t)(M0+row)*512 + k0 + kq);
      Al[row][kq+0] = f2bf(v.x); Al[row][kq+1] = f2bf(v.y);
      Al[row][kq+2] = f2bf(v.z); Al[row][kq+3] = f2bf(v.w);
    }
    #pragma unroll
    for (int i = 0; i < 8; i++){
      int flat = tid*8 + i, kk = flat >> 6, n = flat & 63;
      Bl[n][kk] = Bm[(size_t)(k0+kk)*512 + N0 + n];
    }
    __syncthreads();
    s16x8 a = *(const s16x8*)&Al[mrow][koff];
    #pragma unroll
    for (int i = 0; i < 4; i++){
      s16x8 bb = *(const s16x8*)&Bl[i*16 + (lane & 15)][koff];
      acc[i] = __builtin_amdgcn_mfma_f32_16x16x32_bf16(a, bb, acc[i], 0, 0, 0);
    }
    __syncthreads();
  }
  #pragma unroll
  for (int i = 0; i < 4; i++){
    int n = N0 + i*16 + (lane & 15);
    float bb = bvec[n];
    #pragma unroll
    for (int r = 0; r < 4; r++){
      int m = M0 + w*16 + (lane >> 4)*4 + r;
      int b = m / 800, s = m - b*800;
      unsigned short hv = f2bf(acc[i][r] + bb);
      if (n < 256) kT[(size_t)b*204800 + (size_t)n*800 + s] = hv;
      else         vl[(size_t)b*204800 + (size_t)s*256 + (n-256)] = hv;
    }
  }
}

// ---------------------------------------------------------------------------
// K5/K6: pack LSTM weights as f16 k-pair u32.
// W1p[kk][c], kk<640: rows 2kk,2kk+1 of [W_ih1(768); W_hh1(512)] (2048 cols)
// W2p[kk][c], kk<384: rows 2kk,2kk+1 of [W_ih2(512); W_hh2(256)] (1024 cols)
// ---------------------------------------------------------------------------
__global__ void k_packw1(const float* Wih, const float* Whh, unsigned int* Wp){
  const int kk = blockIdx.x;  // 640
  const int r0 = 2*kk, r1 = r0 + 1;
  const float* row0 = (r0 < 768) ? Wih + (size_t)r0*2048 : Whh + (size_t)(r0-768)*2048;
  const float* row1 = (r1 < 768) ? Wih + (size_t)r1*2048 : Whh + (size_t)(r1-768)*2048;
  for (int c = threadIdx.x; c < 2048; c += 1024)
    Wp[(size_t)kk*2048 + c] = pkh(row0[c], row1[c]);
}
__global__ void k_packw2(const float* Wih, const float* Whh, unsigned int* Wp){
  const int kk = blockIdx.x;  // 384
  const int r0 = 2*kk, r1 = r0 + 1;
  const float* row0 = (r0 < 512) ? Wih + (size_t)r0*1024 : Whh + (size_t)(r0-512)*1024;
  const float* row1 = (r1 < 512) ? Wih + (size_t)r1*1024 : Whh + (size_t)(r1-512)*1024;
  for (int c = threadIdx.x; c < 1024; c += 1024)
    Wp[(size_t)kk*1024 + c] = pkh(row0[c], row1[c]);
}

// ---------------------------------------------------------------------------
// K7: per-batch decode. grid = 64 blocks (one per batch) x 1024 threads.
// ZERO grid barriers: all recurrent state lives in LDS. Weights stream from
// L2 (shared by the 8 blocks of each XCD); K/V via agent loads from LLC.
// ---------------------------------------------------------------------------
__global__ __launch_bounds__(1024) void k_decode(
    const float* b_ih1, const float* b_hh1, const float* b_ih2, const float* b_hh2,
    const unsigned int* W1p, const unsigned int* W2p,
    const float* embW, const float* char_b, const int* lens, const int* y,
    const unsigned short* kT, const unsigned short* vl, const float* keybias,
    const float* ctx0, float* out)
{
  __shared__ unsigned int xall[768]; // f16 pairs: [0..255]emb [256..383]ctx [384..639]h1 [640..767]h2
  __shared__ float g1[2048];
  __shared__ float g2[1024];
  __shared__ float b1s[2048];
  __shared__ float b2s[1024];
  __shared__ float c1s[512];
  __shared__ float c2s[256];
  __shared__ float h2s[256];
  __shared__ float ctxr[256];        // raw (unnormalized) context accumulator
  __shared__ float e_ls[800];
  __shared__ float vpar[8][256];
  __shared__ float oe[512];          // [h2 ; ctx/l] for logits
  __shared__ float redl[16];
  __shared__ float ls_sh;

  const int b = blockIdx.x;
  const int tid = threadIdx.x;
  const int mylen = lens[b];
  float* preds = out;                // [64][250][30]
  float* plot  = out + 480000;       // [800][250]

  // ---- one-time init ----
  for (int i = tid; i < 2048; i += 1024) b1s[i] = b_ih1[i] + b_hh1[i];
  if (tid < 1024) b2s[tid] = b_ih2[tid] + b_hh2[tid];
  if (tid < 512) c1s[tid] = 0.f;
  if (tid < 256){ c2s[tid] = 0.f; h2s[tid] = 0.f; ctxr[tid] = ctx0[b*256 + tid]; }
  if (tid >= 384 && tid < 768) xall[tid] = 0u;  // h1,h2 f16 pairs = 0
  if (tid == 0) ls_sh = 1.f;
  __syncthreads();

  for (int t = 0; t < 250; ++t){
    // ---- A: build xall[0..383] = [emb ; ctx/l] as f16 pairs ----
    {
      const float rl = 1.f / ls_sh;
      if (tid < 256){
        const int tok = (t == 0) ? 0 : y[b*250 + (t-1)];
        const float2 ev = *(const float2*)(embW + (size_t)tok*512 + 2*tid);
        xall[tid] = pkh(ev.x, ev.y);
      } else if (tid < 384){
        const int d = 2*(tid - 256);
        xall[tid] = pkh(ctxr[d]*rl, ctxr[d+1]*rl);
      }
    }
    __syncthreads();

    // ---- B: gates1 — thread computes cols 2tid,2tid+1 over 1280 dims ----
    {
      float a0 = b1s[2*tid], a1 = b1s[2*tid+1];
      const unsigned long long* wp = ((const unsigned long long*)W1p) + tid;
      for (int kk4 = 0; kk4 < 640; kk4 += 4){
        const uint4 xq = *(const uint4*)&xall[kk4];
        #pragma unroll
        for (int j = 0; j < 4; j++){
          const unsigned long long wv = wp[(size_t)(kk4+j)*1024];
          const unsigned int xj = ((const unsigned int*)&xq)[j];
          a0 = dot2(xj, (unsigned int)wv, a0);
          a1 = dot2(xj, (unsigned int)(wv >> 32), a1);
        }
      }
      g1[2*tid] = a0; g1[2*tid+1] = a1;
    }
    __syncthreads();

    // ---- C: LSTM1 — thread i<256 handles dims 2i,2i+1 ----
    if (tid < 256){
      const int d0 = 2*tid, d1 = d0 + 1;
      float h0, h1v;
      { float cn = sigm(g1[512+d0])*c1s[d0] + sigm(g1[d0])*tanhf_(g1[1024+d0]);
        c1s[d0] = cn; h0 = sigm(g1[1536+d0])*tanhf_(cn); }
      { float cn = sigm(g1[512+d1])*c1s[d1] + sigm(g1[d1])*tanhf_(g1[1024+d1]);
        c1s[d1] = cn; h1v = sigm(g1[1536+d1])*tanhf_(cn); }
      xall[384 + tid] = pkh(h0, h1v);
    }
    __syncthreads();

    // ---- D: gates2 — thread = 1 col over 768 dims ([h1;h2]) ----
    {
      float a = b2s[tid];
      for (int kk4 = 0; kk4 < 384; kk4 += 4){
        const uint4 xq = *(const uint4*)&xall[384 + kk4];
        #pragma unroll
        for (int j = 0; j < 4; j++)
          a = dot2(((const unsigned int*)&xq)[j], W2p[(size_t)(kk4+j)*1024 + tid], a);
      }
      g2[tid] = a;
    }
    __syncthreads();

    // ---- E: LSTM2 — thread i<128 handles dims 2i,2i+1 ----
    if (tid < 128){
      const int d0 = 2*tid, d1 = d0 + 1;
      float h0, h1v;
      { float cn = sigm(g2[256+d0])*c2s[d0] + sigm(g2[d0])*tanhf_(g2[512+d0]);
        c2s[d0] = cn; h0 = sigm(g2[768+d0])*tanhf_(cn); }
      { float cn = sigm(g2[256+d1])*c2s[d1] + sigm(g2[d1])*tanhf_(g2[512+d1]);
        c2s[d1] = cn; h1v = sigm(g2[768+d1])*tanhf_(cn); }
      h2s[d0] = h0; h2s[d1] = h1v;
      xall[640 + tid] = pkh(h0, h1v);
    }
    __syncthreads();

    // ---- F: scores — thread s-pair (s0=2tid), dot over 256 k (agent loads) ----
    if (tid < 400){
      float p0 = 0.f, p1 = 0.f;
      const unsigned short* kb = kT + (size_t)b*204800 + 2*tid;
      for (int k4 = 0; k4 < 256; k4 += 4){
        const float4 hq = *(const float4*)&h2s[k4];
        #pragma unroll
        for (int j = 0; j < 4; j++){
          const unsigned int u = aldu(kb + (size_t)(k4+j)*800);
          const float hv = ((const float*)&hq)[j];
          p0 += asf(u << 16) * hv;
          p1 += asf(u & 0xffff0000u) * hv;
        }
      }
      const int s0 = 2*tid;
      e_ls[s0]   = (s0   < mylen) ? __expf(p0 + keybias[b*800 + s0])   : 0.f;
      e_ls[s0+1] = (s0+1 < mylen) ? __expf(p1 + keybias[b*800 + s0+1]) : 0.f;
    }
    __syncthreads();

    // ---- H: context accumulation — thread (g=tid>>7, dd=tid&127), d=2dd ----
    {
      const int g = tid >> 7, dd = tid & 127;
      float a0 = 0.f, a1 = 0.f;
      const int s0 = g*100, sEnd = MINI(s0 + 100, mylen);
      const unsigned short* vp_ = vl + (size_t)b*204800 + (size_t)s0*256 + 2*dd;
      for (int s = s0; s < sEnd; s++){
        const unsigned int u = aldu(vp_); vp_ += 256;
        const float ev = e_ls[s];
        a0 += asf(u << 16) * ev;
        a1 += asf(u & 0xffff0000u) * ev;
      }
      vpar[g][2*dd] = a0; vpar[g][2*dd+1] = a1;
    }
    __syncthreads();

    // ---- G: reduce ctx + softmax denominator ----
    if (tid < 256){
      float ca = vpar[0][tid];
      #pragma unroll
      for (int g = 1; g < 8; g++) ca += vpar[g][tid];
      ctxr[tid] = ca;
      float s4 = e_ls[tid] + e_ls[tid+256] + e_ls[tid+512] + ((tid < 32) ? e_ls[tid+768] : 0.f);
      #pragma unroll
      for (int o = 1; o < 64; o <<= 1) s4 += __shfl_xor(s4, o, 64);
      if ((tid & 63) == 0) redl[tid >> 6] = s4;
    }
    __syncthreads();
    if (tid == 0) ls_sh = redl[0] + redl[1] + redl[2] + redl[3];
    __syncthreads();

    // ---- I: logits inputs oe = [h2 ; ctx/l] ----
    if (tid < 256){
      const float rl = 1.f / ls_sh;
      oe[tid] = h2s[tid];
      oe[256 + tid] = ctxr[tid] * rl;
    }
    __syncthreads();

    // ---- logits (30 vocab) + plot (batch 0) ----
    if (tid < 480){
      const int v = tid >> 4, seg = tid & 15;
      const float* er = embW + (size_t)v*512 + seg*32;
      const float* ov = &oe[seg*32];
      float pc = 0.f;
      #pragma unroll
      for (int j = 0; j < 32; j += 4){
        const float4 e4 = *(const float4*)(er + j);
        pc += ov[j]*e4.x + ov[j+1]*e4.y + ov[j+2]*e4.z + ov[j+3]*e4.w;
      }
      #pragma unroll
      for (int o = 1; o < 16; o <<= 1) pc += __shfl_xor(pc, o, 16);
      if (seg == 0) preds[b*7500 + t*30 + v] = pc + char_b[v];
    }
    if (b == 0 && tid < 800){
      plot[(size_t)tid*250 + t] = e_ls[tid] * (1.f / ls_sh);
    }
    __syncthreads();
  }
}

// ---------------------------------------------------------------------------
extern "C" void kernel_launch(void* const* d_in, const int* in_sizes, int n_in,
                              void* d_out, int out_size, void* d_ws, size_t ws_size,
                              hipStream_t stream){
  const float* enc    = (const float*)d_in[0];
  const float* embW   = (const float*)d_in[1];
  const float* W_ih1  = (const float*)d_in[2];
  const float* b_ih1  = (const float*)d_in[3];
  const float* W_hh1  = (const float*)d_in[4];
  const float* b_hh1  = (const float*)d_in[5];
  const float* W_ih2  = (const float*)d_in[6];
  const float* b_ih2  = (const float*)d_in[7];
  const float* W_hh2  = (const float*)d_in[8];
  const float* b_hh2  = (const float*)d_in[9];
  const float* Wk     = (const float*)d_in[10];
  const float* bk     = (const float*)d_in[11];
  const float* Wv     = (const float*)d_in[12];
  const float* bv     = (const float*)d_in[13];
  const float* Wq     = (const float*)d_in[14];
  const float* bq     = (const float*)d_in[15];
  const float* char_b = (const float*)d_in[16];
  const int*   lens   = (const int*)d_in[17];
  const int*   y      = (const int*)d_in[18];

  char* ws = (char*)d_ws;
  unsigned short* kT   = (unsigned short*)(ws + 0);          // 26,214,400
  unsigned short* vlp  = (unsigned short*)(ws + 26214400);   // 26,214,400
  float* keybias       = (float*)(ws + 52428800);            //    204,800
  unsigned short* Bmat = (unsigned short*)(ws + 52633600);   //    524,288
  float* bvec          = (float*)(ws + 53157888);            //      2,048
  float* wkb           = (float*)(ws + 53159936);            //      2,048
  float* cb0           = (float*)(ws + 53161984);            //      1,024
  float* ctx0          = (float*)(ws + 53163008);            //     65,536
  unsigned int* W1p    = (unsigned int*)(ws + 53228544);     //  5,242,880
  unsigned int* W2p    = (unsigned int*)(ws + 58471424);     //  1,572,864
  // total: 60,044,288 bytes
  float* out = (float*)d_out;

  k_prepw<<<512, 256, 0, stream>>>(Wk, Wq, Wv, bk, bq, bv, Bmat, bvec, wkb, cb0);
  k_keybias<<<6400, 512, 0, stream>>>(enc, wkb, cb0, keybias);
  k_init<<<64, 256, 0, stream>>>(enc, Wk, bk, ctx0);
  k_gemm<<<6400, 256, 0, stream>>>(enc, Bmat, bvec, kT, vlp);
  k_packw1<<<640, 1024, 0, stream>>>(W_ih1, W_hh1, W1p);
  k_packw2<<<384, 1024, 0, stream>>>(W_ih2, W_hh2, W2p);
  k_decode<<<64, 1024, 0, stream>>>(b_ih1, b_hh1, b_ih2, b_hh2, W1p, W2p,
                                    embW, char_b, lens, y, kT, vlp, keybias,
                                    ctx0, out);
}

// Round 10
// 12384.892 us; speedup vs baseline: 2.6366x; 2.6366x over previous
//
#include <hip/hip_runtime.h>

typedef float f32x4 __attribute__((ext_vector_type(4)));
typedef short s16x8 __attribute__((ext_vector_type(8)));

#define MINI(a,b) ((a)<(b)?(a):(b))
#define MAXI(a,b) ((a)>(b)?(a):(b))

static __device__ __forceinline__ float bf2f(unsigned short u){
  union { unsigned int i; float f; } x; x.i = ((unsigned int)u) << 16; return x.f;
}
static __device__ __forceinline__ unsigned short f2bf(float f){
  union { float f; unsigned int i; } x; x.f = f;
  return (unsigned short)((x.i + 0x7fffu + ((x.i >> 16) & 1u)) >> 16);
}
static __device__ __forceinline__ float sigm(float x){ return 1.f / (1.f + __expf(-x)); }
static __device__ __forceinline__ float tanhf_(float x){ return 1.f - 2.f / (1.f + __expf(2.f * x)); }

// --- per-access agent coherence (sc1 ops at LLC; no cache-wide inv/wb) ---
static __device__ __forceinline__ float ald1(const float* p){
  return __hip_atomic_load(p, __ATOMIC_RELAXED, __HIP_MEMORY_SCOPE_AGENT);
}
static __device__ __forceinline__ void ast1(float* p, float v){
  __hip_atomic_store(p, v, __ATOMIC_RELAXED, __HIP_MEMORY_SCOPE_AGENT);
}
static __device__ __forceinline__ float2 ald2(const float* p){
  unsigned long long u = __hip_atomic_load((const unsigned long long*)p,
                          __ATOMIC_RELAXED, __HIP_MEMORY_SCOPE_AGENT);
  union { unsigned long long u; float2 f; } c; c.u = u; return c.f;
}
static __device__ __forceinline__ void ast2(float* p, float a, float b){
  union { unsigned long long u; float f[2]; } c; c.f[0] = a; c.f[1] = b;
  __hip_atomic_store((unsigned long long*)p, c.u, __ATOMIC_RELAXED, __HIP_MEMORY_SCOPE_AGENT);
}
static __device__ __forceinline__ unsigned long long ald64(const void* p){
  return __hip_atomic_load((const unsigned long long*)p, __ATOMIC_RELAXED, __HIP_MEMORY_SCOPE_AGENT);
}
static __device__ __forceinline__ void ast32(unsigned short* p, unsigned int v){
  __hip_atomic_store((unsigned int*)p, v, __ATOMIC_RELAXED, __HIP_MEMORY_SCOPE_AGENT);
}
static __device__ __forceinline__ void aadd(float* p, float v){
  __hip_atomic_fetch_add(p, v, __ATOMIC_RELAXED, __HIP_MEMORY_SCOPE_AGENT);
}

// ---------------------------------------------------------------------------
// K1: fold Wq into key projection (Bmat bf16), biases.
// ---------------------------------------------------------------------------
__global__ void k_prepw(const float* Wk, const float* Wq, const float* Wv,
                        const float* bk, const float* bq, const float* bv,
                        unsigned short* Bm, float* bvec, float* wkb, float* cb0){
  const int k = blockIdx.x;     // 512
  const int t = threadIdx.x;    // 256
  const float scale = 0.0625f;
  float acc = 0.f;
  for (int p = 0; p < 256; p++) acc += Wk[k*256+p] * Wq[t*256+p];
  Bm[(size_t)k*512 + t]       = f2bf(acc * scale);
  Bm[(size_t)k*512 + 256 + t] = f2bf(Wv[k*256+t]);
  __shared__ float red[256];
  red[t] = Wk[k*256+t] * bq[t];
  __syncthreads();
  for (int o = 128; o > 0; o >>= 1){ if (t < o) red[t] += red[t+o]; __syncthreads(); }
  if (t == 0) wkb[k] = red[0] * scale;
  if (k == 0){
    float a2 = 0.f;
    for (int p = 0; p < 256; p++) a2 += bk[p] * Wq[t*256+p];
    bvec[t] = a2 * scale;
    bvec[256+t] = bv[t];
    __syncthreads();
    red[t] = bk[t] * bq[t];
    __syncthreads();
    for (int o = 128; o > 0; o >>= 1){ if (t < o) red[t] += red[t+o]; __syncthreads(); }
    if (t == 0) *cb0 = red[0] * scale;
  }
}

__global__ void k_keybias(const float* enc, const float* wkb, const float* cb0,
                          float* keybias){
  const int m = blockIdx.x*8 + (threadIdx.x >> 6);
  const int lane = threadIdx.x & 63;
  float p = 0.f;
  #pragma unroll
  for (int j = 0; j < 8; j++){ int k = lane + 64*j; p += enc[(size_t)m*512 + k] * wkb[k]; }
  #pragma unroll
  for (int o = 1; o < 64; o <<= 1) p += __shfl_xor(p, o, 64);
  if (lane == 0) keybias[m] = p + *cb0;
}

// ---------------------------------------------------------------------------
// K3: init: ctx(parity0)=key_proj[:,0,:] f32, l=1, zero h1/h2/c1/c2/ctrs.
// ---------------------------------------------------------------------------
__global__ void k_init(const float* enc, const float* Wk, const float* bk,
                       float* ctx, float* la, unsigned short* h1bf,
                       unsigned short* h2bf, float* h2f, float* c1p, float* c2p,
                       unsigned int* ctr){
  const int b = blockIdx.x, t = threadIdx.x;  // 64 x 256
  float acc = bk[t];
  const float* er = enc + (size_t)b*800*512;
  for (int k = 0; k < 512; k++) acc += er[k] * Wk[(size_t)k*256 + t];
  ctx[b*256 + t] = acc;
  if (t == 0) la[b] = 1.f;
  const int id = b*256 + t;           // 0..16383
  unsigned int* h1u = (unsigned int*)h1bf;   // 32768 uints (2 bufs)
  h1u[id] = 0u; h1u[16384 + id] = 0u;
  unsigned int* h2u = (unsigned int*)h2bf;   // 16384 uints (2 bufs)
  h2u[id] = 0u;
  h2f[id] = 0.f; h2f[16384 + id] = 0.f;
  c1p[id] = 0.f; c1p[16384 + id] = 0.f;      // 256 blocks * 128
  c2p[id] = 0.f;                             // 128 blocks * 128
  if (b == 0){ for (int i = t; i < 1024; i += 256) ctr[i] = 0u; }
}

// ---------------------------------------------------------------------------
// K4: MFMA bf16 GEMM; epilogue scatters to keyT[b][k][s] and val[b][s][d].
// ---------------------------------------------------------------------------
__global__ __launch_bounds__(256) void k_gemm(const float* enc, const unsigned short* Bm,
                                              const float* bvec,
                                              unsigned short* kT, unsigned short* vl){
  __shared__ unsigned short Al[64][40];
  __shared__ unsigned short Bl[64][40];
  const int tid = threadIdx.x, w = tid >> 6, lane = tid & 63;
  const int M0 = (blockIdx.x >> 3) * 64;
  const int N0 = (blockIdx.x & 7) * 64;
  f32x4 acc[4] = {};
  const int mrow = w*16 + (lane & 15);
  const int koff = (lane >> 4) * 8;
  for (int k0 = 0; k0 < 512; k0 += 32){
    #pragma unroll
    for (int it = 0; it < 2; it++){
      int row = (tid >> 3) + it*32, kq = (tid & 7) * 4;
      float4 v = *(const float4*)(enc + (size_t)(M0+row)*512 + k0 + kq);
      Al[row][kq+0] = f2bf(v.x); Al[row][kq+1] = f2bf(v.y);
      Al[row][kq+2] = f2bf(v.z); Al[row][kq+3] = f2bf(v.w);
    }
    #pragma unroll
    for (int i = 0; i < 8; i++){
      int flat = tid*8 + i, kk = flat >> 6, n = flat & 63;
      Bl[n][kk] = Bm[(size_t)(k0+kk)*512 + N0 + n];
    }
    __syncthreads();
    s16x8 a = *(const s16x8*)&Al[mrow][koff];
    #pragma unroll
    for (int i = 0; i < 4; i++){
      s16x8 bb = *(const s16x8*)&Bl[i*16 + (lane & 15)][koff];
      acc[i] = __builtin_amdgcn_mfma_f32_16x16x32_bf16(a, bb, acc[i], 0, 0, 0);
    }
    __syncthreads();
  }
  #pragma unroll
  for (int i = 0; i < 4; i++){
    int n = N0 + i*16 + (lane & 15);
    float bb = bvec[n];
    #pragma unroll
    for (int r = 0; r < 4; r++){
      int m = M0 + w*16 + (lane >> 4)*4 + r;
      int b = m / 800, s = m - b*800;
      unsigned short hv = f2bf(acc[i][r] + bb);
      if (n < 256) kT[(size_t)b*204800 + (size_t)n*800 + s] = hv;
      else         vl[(size_t)b*204800 + (size_t)s*256 + (n-256)] = hv;
    }
  }
}

// ---------------------------------------------------------------------------
// Leader/flag grid barrier (256 blocks). 16 arrival lines; block 0 aggregates
// and publishes the generation to 16 REPLICATED flag lines.
// ---------------------------------------------------------------------------
static __device__ __forceinline__ void gbar(unsigned int* ctrs, unsigned int* gen){
  __syncthreads();
  if (threadIdx.x == 0){
    *gen += 256u;
    const unsigned int target = *gen;
    __hip_atomic_fetch_add(&ctrs[(blockIdx.x & 15) * 32], 1u,
                           __ATOMIC_RELAXED, __HIP_MEMORY_SCOPE_AGENT);
    if (blockIdx.x == 0){
      for (;;){
        unsigned int s = 0;
        #pragma unroll
        for (int i = 0; i < 16; i++)
          s += __hip_atomic_load(&ctrs[i * 32], __ATOMIC_RELAXED, __HIP_MEMORY_SCOPE_AGENT);
        if (s >= target) break;
        __builtin_amdgcn_s_sleep(2);
      }
      #pragma unroll
      for (int i = 0; i < 16; i++)
        __hip_atomic_store(&ctrs[512 + i*32], target, __ATOMIC_RELAXED, __HIP_MEMORY_SCOPE_AGENT);
    } else {
      unsigned int* fl = &ctrs[512 + (blockIdx.x & 15)*32];
      while (__hip_atomic_load(fl, __ATOMIC_RELAXED, __HIP_MEMORY_SCOPE_AGENT) < target)
        __builtin_amdgcn_s_sleep(4);
    }
  }
  __syncthreads();
}

// ---------------------------------------------------------------------------
// Register-LEAN dot helpers. The VGPR cap at 1024 threads is 64 and immovable
// (rounds 2-7); rounds 1-7 spilled ~50 MB/step to scratch (WRITE_SIZE 10-13 GB
// vs round-8's 8.5 KB). These bursts keep <=16 data regs in flight.
// ---------------------------------------------------------------------------
// bf16 dot: 32-dim bursts (8 independent u64 loads), 16-dim tail. k0,k1 mult 16.
static __device__ __forceinline__ void dot_bf16(const unsigned short* xg, int k0, int k1,
                                                const float (*W)[8], float* acc){
  const unsigned long long* p = (const unsigned long long*)xg;
  int k = k0;
  while (k + 32 <= k1){
    unsigned long long v[8];
    #pragma unroll
    for (int i = 0; i < 8; i++) v[i] = ald64(p + (k >> 2) + i);
    #pragma unroll
    for (int i = 0; i < 8; i++){
      float xv[4];
      xv[0] = bf2f((unsigned short)v[i]);
      xv[1] = bf2f((unsigned short)(v[i] >> 16));
      xv[2] = bf2f((unsigned short)(v[i] >> 32));
      xv[3] = bf2f((unsigned short)(v[i] >> 48));
      #pragma unroll
      for (int d = 0; d < 4; d++){
        const float* wr = W[k + i*4 + d];
        #pragma unroll
        for (int cc = 0; cc < 8; cc++) acc[cc] += xv[d] * wr[cc];
      }
    }
    k += 32;
  }
  if (k < k1){
    unsigned long long v[4];
    #pragma unroll
    for (int i = 0; i < 4; i++) v[i] = ald64(p + (k >> 2) + i);
    #pragma unroll
    for (int i = 0; i < 4; i++){
      float xv[4];
      xv[0] = bf2f((unsigned short)v[i]);
      xv[1] = bf2f((unsigned short)(v[i] >> 16));
      xv[2] = bf2f((unsigned short)(v[i] >> 32));
      xv[3] = bf2f((unsigned short)(v[i] >> 48));
      #pragma unroll
      for (int d = 0; d < 4; d++){
        const float* wr = W[k + i*4 + d];
        #pragma unroll
        for (int cc = 0; cc < 8; cc++) acc[cc] += xv[d] * wr[cc];
      }
    }
  }
}

// f32 dot: 16-dim bursts (8 independent float2 sc1 loads = 16 regs).
static __device__ __forceinline__ void dot_f32(const float* xg, int k0, int k1,
                                               const float (*W)[8], float* acc){
  for (int k = k0; k < k1; k += 16){
    float2 v[8];
    #pragma unroll
    for (int i = 0; i < 8; i++) v[i] = ald2(xg + k + 2*i);
    #pragma unroll
    for (int i = 0; i < 8; i++){
      const float* w0 = W[k + 2*i];
      const float* w1 = W[k + 2*i + 1];
      #pragma unroll
      for (int cc = 0; cc < 8; cc++) acc[cc] += v[i].x*w0[cc] + v[i].y*w1[cc];
    }
  }
}

__global__ __launch_bounds__(1024) void k_decode(
    const float* W_ih1, const float* b_ih1, const float* W_hh1, const float* b_hh1,
    const float* W_ih2, const float* b_ih2, const float* W_hh2, const float* b_hh2,
    const float* embW, const float* char_b, const int* lens, const int* y,
    const unsigned short* kT, const unsigned short* vl, const float* keybias,
    unsigned short* h1bf, unsigned short* h2bf, float* h2f,
    float* ctxacc, float* lacc, float* c1p, float* c2p,
    float* esc, unsigned int* ctr, float* out)
{
  __shared__ float W1s[1280][8];   // 40 KB
  __shared__ float W2s[768][8];    // 24 KB
  __shared__ float b1s[8];
  __shared__ float b2s[8];
  __shared__ float embrow[512];
  __shared__ float chb;
  __shared__ float redA[16][8][64]; // 32 KB
  __shared__ float g1s[8][64];
  __shared__ float partA[16][256];  // 16 KB: attention partials
  __shared__ float e_l[256];
  __shared__ float h2loc[256];

  const int bi = blockIdx.x;
  const int tid = threadIdx.x;   // 0..1023
  const int w = tid >> 6;        // 0..15
  const int lane = tid & 63;

  for (int idx = tid; idx < 1280*8; idx += 1024){
    int k = idx >> 3, c = idx & 7;
    int col = ((c >> 1) << 9) + 2*bi + (c & 1);
    W1s[k][c] = (k < 768) ? W_ih1[(size_t)k*2048 + col] : W_hh1[(size_t)(k-768)*2048 + col];
  }
  if (bi < 128){
    for (int idx = tid; idx < 768*8; idx += 1024){
      int k = idx >> 3, c = idx & 7;
      int col = ((c >> 1) << 8) + 2*bi + (c & 1);
      W2s[k][c] = (k < 512) ? W_ih2[(size_t)k*1024 + col] : W_hh2[(size_t)(k-512)*1024 + col];
    }
    if (tid < 8){ int col = ((tid >> 1) << 8) + 2*bi + (tid & 1); b2s[tid] = b_ih2[col] + b_hh2[col]; }
  }
  if (tid < 8){ int col = ((tid >> 1) << 9) + 2*bi + (tid & 1); b1s[tid] = b_ih1[col] + b_hh1[col]; }
  if (bi >= 128 && bi < 158){
    if (tid < 512) embrow[tid] = embW[(bi-128)*512 + tid];
    if (tid == 0) chb = char_b[bi-128];
  }
  __syncthreads();

  unsigned int gen = 0;
  const int myb = bi & 63;
  const int sc  = bi >> 6;
  const int mylen = lens[myb];
  const int sbase = sc * 200;

  float* preds = out;            // [64][250][30]
  float* plot  = out + 480000;   // [800][250]

  for (int t = 0; t < 250; ++t){
    const int p  = t & 1;
    const int np = 1 - p;
    const unsigned short* h1p_bf = h1bf + p*(64*512);
    unsigned short*       h1n_bf = h1bf + np*(64*512);
    const unsigned short* h2p_bf = h2bf + p*(64*256);
    unsigned short*       h2n_bf = h2bf + np*(64*256);
    const float* h2f_p = h2f + p*(64*256);
    float*       h2f_np= h2f + np*(64*256);
    const float* ca_p  = ctxacc + p*(64*256);
    float*       ca_np = ctxacc + np*(64*256);
    const float* la_p  = lacc + p*64;
    float*       la_np = lacc + np*64;

    // ---------------- Phase 1: gates1 + LSTM1 (16 waves, 80 dims each) --------
    {
      float acc[8]  = {0,0,0,0,0,0,0,0};
      float accB[8] = {0,0,0,0,0,0,0,0};
      const int b = lane;
      const int tok = (t == 0) ? 0 : y[b*250 + (t-1)];
      const float* erow = embW + (size_t)tok*512;            // plain cached
      const float* crow = ca_p + b*256 - 512;                // f32 sc1
      const unsigned short* hrow = h1p_bf + b*512 - 768;     // bf16 sc1
      const int k0 = w*80, k1 = k0 + 80;
      const int a1 = MINI(k1, 512);
      for (int k = k0; k < a1; k += 4){
        float4 xv = *(const float4*)(erow + k);
        const float* w0 = W1s[k]; const float* w1 = W1s[k+1];
        const float* w2 = W1s[k+2]; const float* w3 = W1s[k+3];
        #pragma unroll
        for (int cc = 0; cc < 8; cc++)
          acc[cc] += xv.x*w0[cc] + xv.y*w1[cc] + xv.z*w2[cc] + xv.w*w3[cc];
      }
      dot_f32(crow, MAXI(k0,512), MINI(k1,768), W1s, accB);
      dot_bf16(hrow, MAXI(k0,768), k1, W1s, acc);
      const float rl = 1.f / ald1(&la_p[b]);
      #pragma unroll
      for (int c = 0; c < 8; c++) redA[w][c][b] = acc[c] + accB[c]*rl;
    }
    __syncthreads();
    if (tid < 512){
      int c = tid >> 6, b = tid & 63;
      float g = b1s[c];
      #pragma unroll
      for (int ww = 0; ww < 16; ww++) g += redA[ww][c][b];
      g1s[c][b] = g;
    }
    __syncthreads();
    if (w == 0){   // LSTM1 cell: dims 2bi, 2bi+1
      int b = lane;
      float h0, h1v;
      { float gi=g1s[0][b], gf=g1s[2][b], gg=g1s[4][b], go=g1s[6][b];
        float co = c1p[bi*128 + 2*b];
        float cn = sigm(gf)*co + sigm(gi)*tanhf_(gg);
        c1p[bi*128 + 2*b] = cn; h0 = sigm(go)*tanhf_(cn); }
      { float gi=g1s[1][b], gf=g1s[3][b], gg=g1s[5][b], go=g1s[7][b];
        float co = c1p[bi*128 + 2*b + 1];
        float cn = sigm(gf)*co + sigm(gi)*tanhf_(gg);
        c1p[bi*128 + 2*b + 1] = cn; h1v = sigm(go)*tanhf_(cn); }
      unsigned int pk = (unsigned int)f2bf(h0) | ((unsigned int)f2bf(h1v) << 16);
      ast32(h1n_bf + b*512 + 2*bi, pk);
    }
    gbar(ctr, &gen);  // SYNC1: h1 ready

    // ---------------- Phase 2 (split by block role) ----------------
    if (bi < 128){
      // gates2 + LSTM2: dims 2bi, 2bi+1; 16 waves x 48 dims
      {
        float acc2[8] = {0,0,0,0,0,0,0,0};
        const int b = lane;
        const unsigned short* h1r = h1n_bf + b*512;
        const unsigned short* h2r = h2p_bf + b*256 - 512;
        const int k0 = w*48, k1 = k0 + 48;
        dot_bf16(h1r, k0, MINI(k1,512), W2s, acc2);
        dot_bf16(h2r, MAXI(k0,512), k1, W2s, acc2);
        #pragma unroll
        for (int c = 0; c < 8; c++) redA[w][c][lane] = acc2[c];
      }
      __syncthreads();
      if (tid < 512){
        int c = tid >> 6, b = tid & 63;
        float g = b2s[c];
        #pragma unroll
        for (int ww = 0; ww < 16; ww++) g += redA[ww][c][b];
        g1s[c][b] = g;
      }
      __syncthreads();
      if (w == 0){
        int b = lane;
        float h0, h1v;
        { float gi=g1s[0][b], gf=g1s[2][b], gg=g1s[4][b], go=g1s[6][b];
          float co = c2p[bi*128 + 2*b];
          float cn = sigm(gf)*co + sigm(gi)*tanhf_(gg);
          c2p[bi*128 + 2*b] = cn; h0 = sigm(go)*tanhf_(cn); }
        { float gi=g1s[1][b], gf=g1s[3][b], gg=g1s[5][b], go=g1s[7][b];
          float co = c2p[bi*128 + 2*b + 1];
          float cn = sigm(gf)*co + sigm(gi)*tanhf_(gg);
          c2p[bi*128 + 2*b + 1] = cn; h1v = sigm(go)*tanhf_(cn); }
        unsigned int pk = (unsigned int)f2bf(h0) | ((unsigned int)f2bf(h1v) << 16);
        ast32(h2n_bf + b*256 + 2*bi, pk);
        ast2(h2f_np + b*256 + 2*bi, h0, h1v);
      }
    } else if (bi < 158){
      // logits for step t-1 (register-lean: 8 float2 bursts, was v[32]=64 regs)
      if (t > 0){
        if (tid < 512){
          int b3 = tid & 63, ch = tid >> 6;
          const float* base = (ch < 4) ? (h2f_p + b3*256 + ch*64)
                                       : (ca_p  + b3*256 + (ch-4)*64);
          const float* er = &embrow[(ch < 4) ? ch*64 : 256 + (ch-4)*64];
          float pc = 0.f;
          for (int c4 = 0; c4 < 4; c4++){
            float2 v[8];
            #pragma unroll
            for (int i = 0; i < 8; i++) v[i] = ald2(base + c4*16 + 2*i);
            #pragma unroll
            for (int i = 0; i < 8; i++)
              pc += v[i].x*er[c4*16 + 2*i] + v[i].y*er[c4*16 + 2*i + 1];
          }
          if (ch >= 4) pc *= 1.f / ald1(&la_p[b3]);
          g1s[ch][b3] = pc;
        }
        __syncthreads();
        if (tid < 64){
          float s2 = chb;
          #pragma unroll
          for (int c = 0; c < 8; c++) s2 += g1s[c][tid];
          preds[tid*7500 + (t-1)*30 + (bi-128)] = s2;
        }
      }
    } else if (bi < 190){
      if (t > 0 && tid < 25){
        int s3 = (bi-158)*25 + tid;
        plot[(size_t)s3*250 + (t-1)] = ald1(&esc[s3]) * (1.f / ald1(&la_p[0]));
      }
    } else if (bi < 254){
      if (tid < 128) ast2(&ca_np[(bi-190)*256 + 2*tid], 0.f, 0.f);
    } else if (bi == 254){
      if (tid < 64) ast1(&la_np[tid], 0.f);
    }
    gbar(ctr, &gen);  // SYNC2: h2 ready, accumulators zeroed

    // ---------------- Phase 3: attention (16 waves; s-quarter) ----------------
    {
      if (tid < 128){ float2 hv = ald2(&h2f_np[myb*256 + 2*tid]);
                      h2loc[2*tid] = hv.x; h2loc[2*tid+1] = hv.y; }
      __syncthreads();
      const int qlen = MINI(200, MAXI(0, mylen - sbase));
      // K-dot: wave w owns k = 16w..16w+15; lane owns s = sbase+4*lane..+3.
      // unroll 8: 8 u64 in flight (16 regs), 2 rounds.
      {
        float ps0=0.f, ps1=0.f, ps2=0.f, ps3=0.f;
        if (4*lane < qlen){
          const float* hl = &h2loc[w*16];
          const unsigned short* kb = kT + (size_t)myb*204800 + (size_t)(w*16)*800 + sbase + 4*lane;
          #pragma unroll 8
          for (int kk = 0; kk < 16; kk++){
            const unsigned long long u = *(const unsigned long long*)(kb + (size_t)kk*800);
            const float hv = hl[kk];
            ps0 += bf2f((unsigned short)(u      )) * hv;
            ps1 += bf2f((unsigned short)(u >> 16)) * hv;
            ps2 += bf2f((unsigned short)(u >> 32)) * hv;
            ps3 += bf2f((unsigned short)(u >> 48)) * hv;
          }
        }
        partA[w][4*lane+0] = ps0; partA[w][4*lane+1] = ps1;
        partA[w][4*lane+2] = ps2; partA[w][4*lane+3] = ps3;
      }
      __syncthreads();
      if (tid < 256){
        float e = 0.f;
        if (tid < qlen){
          float sc_ = partA[0][tid];
          #pragma unroll
          for (int q = 1; q < 16; q++) sc_ += partA[q][tid];
          e = __expf(sc_ + keybias[myb*800 + sbase + tid]);
        }
        e_l[tid] = e;
        if (myb == 0 && tid < 200) ast1(&esc[sbase + tid], e);
      }
      __syncthreads();
      if (w == 0){
        float s4 = e_l[lane] + e_l[lane+64] + e_l[lane+128] + e_l[lane+192];
        #pragma unroll
        for (int o = 1; o < 64; o <<= 1) s4 += __shfl_xor(s4, o, 64);
        if (lane == 0) aadd(&la_np[myb], s4);
      }
      // V: wave w owns j = 13w..+12; unroll 4 (8 data regs in flight).
      {
        float va0=0.f, va1=0.f, va2=0.f, va3=0.f;
        const int j0 = w*13;
        if (j0 < qlen){
          const unsigned short* vp = vl + (size_t)myb*204800 + (size_t)(sbase + j0)*256 + 4*lane;
          #pragma unroll 4
          for (int jj = 0; jj < 13; jj++){
            const float ev = e_l[j0 + jj];
            const unsigned long long u = *(const unsigned long long*)(vp + (size_t)jj*256);
            va0 += bf2f((unsigned short)(u      )) * ev;
            va1 += bf2f((unsigned short)(u >> 16)) * ev;
            va2 += bf2f((unsigned short)(u >> 32)) * ev;
            va3 += bf2f((unsigned short)(u >> 48)) * ev;
          }
        }
        __syncthreads();   // partA K-partials consumed above; safe to overwrite
        partA[w][4*lane+0] = va0; partA[w][4*lane+1] = va1;
        partA[w][4*lane+2] = va2; partA[w][4*lane+3] = va3;
      }
      __syncthreads();
      if (tid < 256){
        float s5 = partA[0][tid];
        #pragma unroll
        for (int q = 1; q < 16; q++) s5 += partA[q][tid];
        aadd(&ca_np[myb*256 + tid], s5);
      }
    }
    gbar(ctr, &gen);  // SYNC3: context accumulated
  }

  // ---------------- epilogue: outputs for step 249 (parity 0 buffers) ----------------
  {
    const float* h2f_p = h2f;        // parity 0
    const float* ca_p  = ctxacc;
    const float* la_p  = lacc;
    if (bi >= 128 && bi < 158){
      if (tid < 512){
        int b3 = tid & 63, ch = tid >> 6;
        const float* base = (ch < 4) ? (h2f_p + b3*256 + ch*64)
                                     : (ca_p  + b3*256 + (ch-4)*64);
        const float* er = &embrow[(ch < 4) ? ch*64 : 256 + (ch-4)*64];
        float pc = 0.f;
        for (int c4 = 0; c4 < 4; c4++){
          float2 v[8];
          #pragma unroll
          for (int i = 0; i < 8; i++) v[i] = ald2(base + c4*16 + 2*i);
          #pragma unroll
          for (int i = 0; i < 8; i++)
            pc += v[i].x*er[c4*16 + 2*i] + v[i].y*er[c4*16 + 2*i + 1];
        }
        if (ch >= 4) pc *= 1.f / ald1(&la_p[b3]);
        g1s[ch][b3] = pc;
      }
      __syncthreads();
      if (tid < 64){
        float s2 = chb;
        #pragma unroll
        for (int c = 0; c < 8; c++) s2 += g1s[c][tid];
        preds[tid*7500 + 249*30 + (bi-128)] = s2;
      }
    } else if (bi >= 158 && bi < 190){
      if (tid < 25){
        int s3 = (bi-158)*25 + tid;
        plot[(size_t)s3*250 + 249] = ald1(&esc[s3]) * (1.f / ald1(&la_p[0]));
      }
    }
  }
}

// ---------------------------------------------------------------------------
extern "C" void kernel_launch(void* const* d_in, const int* in_sizes, int n_in,
                              void* d_out, int out_size, void* d_ws, size_t ws_size,
                              hipStream_t stream){
  const float* enc    = (const float*)d_in[0];
  const float* embW   = (const float*)d_in[1];
  const float* W_ih1  = (const float*)d_in[2];
  const float* b_ih1  = (const float*)d_in[3];
  const float* W_hh1  = (const float*)d_in[4];
  const float* b_hh1  = (const float*)d_in[5];
  const float* W_ih2  = (const float*)d_in[6];
  const float* b_ih2  = (const float*)d_in[7];
  const float* W_hh2  = (const float*)d_in[8];
  const float* b_hh2  = (const float*)d_in[9];
  const float* Wk     = (const float*)d_in[10];
  const float* bk     = (const float*)d_in[11];
  const float* Wv     = (const float*)d_in[12];
  const float* bv     = (const float*)d_in[13];
  const float* Wq     = (const float*)d_in[14];
  const float* bq     = (const float*)d_in[15];
  const float* char_b = (const float*)d_in[16];
  const int*   lens   = (const int*)d_in[17];
  const int*   y      = (const int*)d_in[18];

  char* ws = (char*)d_ws;
  unsigned short* kT   = (unsigned short*)(ws + 0);          // 26,214,400
  unsigned short* vlp  = (unsigned short*)(ws + 26214400);   // 26,214,400
  float* keybias       = (float*)(ws + 52428800);            //    204,800
  unsigned short* Bmat = (unsigned short*)(ws + 52633600);   //    524,288
  float* bvec          = (float*)(ws + 53157888);            //      2,048
  float* wkb           = (float*)(ws + 53159936);            //      2,048
  float* cb0           = (float*)(ws + 53161984);            //      1,024
  unsigned short* h1bf = (unsigned short*)(ws + 53163008);   //    131,072 (2 bufs)
  unsigned short* h2bf = (unsigned short*)(ws + 53294080);   //     65,536 (2 bufs)
  float* h2f           = (float*)(ws + 53359616);            //    262,144 (2 bufs)
  float* ctxacc        = (float*)(ws + 53621760);            //    131,072 (2 bufs)
  float* lacc          = (float*)(ws + 53752832);            //      1,024 (2 bufs)
  float* c1p           = (float*)(ws + 53753856);            //    131,072
  float* c2p           = (float*)(ws + 53884928);            //     65,536
  float* esc           = (float*)(ws + 53950464);            //      4,096
  unsigned int* ctr    = (unsigned int*)(ws + 53954560);     //      4,096
  float* out = (float*)d_out;

  k_prepw<<<512, 256, 0, stream>>>(Wk, Wq, Wv, bk, bq, bv, Bmat, bvec, wkb, cb0);
  k_keybias<<<6400, 512, 0, stream>>>(enc, wkb, cb0, keybias);
  k_init<<<64, 256, 0, stream>>>(enc, Wk, bk, ctxacc, lacc, h1bf, h2bf, h2f, c1p, c2p, ctr);
  k_gemm<<<6400, 256, 0, stream>>>(enc, Bmat, bvec, kT, vlp);
  k_decode<<<256, 1024, 0, stream>>>(W_ih1, b_ih1, W_hh1, b_hh1, W_ih2, b_ih2, W_hh2, b_hh2,
                                     embW, char_b, lens, y, kT, vlp, keybias,
                                     h1bf, h2bf, h2f, ctxacc, lacc, c1p, c2p, esc, ctr, out);
}